// Round 11
// baseline (252.735 us; speedup 1.0000x reference)
//
#include <hip/hip_runtime.h>
#include <math.h>

#define CHI 64
#define CHO 64
#define HH 128
#define WW 128
#define NB 4
#define KK 9
#define NOFF 27
#define EPSV 1e-5f
#define PLANE (HH * WW)
#define SP 72                 // LDS ci-stride (bytes=144: 16B-aligned, uniform banks)

typedef float v2f __attribute__((ext_vector_type(2)));
typedef float f2v __attribute__((ext_vector_type(2), aligned(4)));
typedef float f32x4 __attribute__((ext_vector_type(4)));
typedef short bf16x8 __attribute__((ext_vector_type(8)));

__device__ __forceinline__ v2f pkfma(v2f a, v2f b, v2f c) {
#if __has_builtin(__builtin_elementwise_fma)
    return __builtin_elementwise_fma(a, b, c);
#else
    return a * b + c;
#endif
}

// fp32 -> bf16 round-to-nearest-even
__device__ __forceinline__ unsigned short f2bf(float f) {
    unsigned u = __float_as_uint(f);
    u += 0x7fff + ((u >> 16) & 1);
    return (unsigned short)(u >> 16);
}

// ---------------- prep: pack MFMA A-fragment tables (bf16) ----------------
// A-frag layout (mfma_f32_16x16x32_bf16): lane holds A[m=lane&15][k=(lane>>4)*8+j]
// w_bf  (deform):  elem = (((kk*4+ct)*2+ks)*64 + lane)*8 + j ; co=ct*16+m, ci=ks*32+k
// woA (off_conv):  elem = (((kk*2+ks)*2+ct)*64 + lane)*8 + j ; c =ct*16+m (0 if >=27)
__global__ __launch_bounds__(256) void prep_kernel(const float* __restrict__ w,
                                                   const float* __restrict__ w_off,
                                                   unsigned short* __restrict__ w_bf,
                                                   unsigned short* __restrict__ woA) {
    int i = blockIdx.x * 256 + threadIdx.x;    // grid 144*256 = 36864 exactly
    {
        int j    = i & 7;
        int lane = (i >> 3) & 63;
        int ks   = (i >> 9) & 1;
        int ct   = (i >> 10) & 3;
        int kk   = i >> 12;                    // 0..8
        int co   = ct * 16 + (lane & 15);
        int ci   = ks * 32 + ((lane >> 4) & 3) * 8 + j;
        w_bf[i]  = f2bf(w[(co * CHI + ci) * KK + kk]);
    }
    if (i < 18432) {
        int j    = i & 7;
        int lane = (i >> 3) & 63;
        int ct   = (i >> 9) & 1;
        int ks   = (i >> 10) & 1;
        int kk   = i >> 11;                    // 0..8
        int c    = ct * 16 + (lane & 15);
        int ci   = ks * 32 + (lane >> 4) * 8 + j;
        woA[i]   = (c < NOFF) ? f2bf(w_off[(c * CHI + ci) * KK + kk]) : (unsigned short)0;
    }
}

// ---------------- offset conv via MFMA ----------------
// Block 256 = 4 waves, half-row (64 px) x all 27 co. Stage x window
// (3 rows x 66 px x 64 ci) as bf16 in LDS, then 9 taps x K=64 MFMA.
// Staging loop unrolled x4 for MLP; kk loop unrolled x3 so next A-loads
// overlap current MFMAs. grid 1024: blockIdx%8 -> (b, h-half) XCD swizzle.
__global__ __launch_bounds__(256) void off_conv_kernel(const float* __restrict__ x,
                                                       const unsigned short* __restrict__ woA,
                                                       float* __restrict__ off) {
    const int id    = blockIdx.x;
    const int slot  = id & 7;
    const int b     = slot >> 1;
    const int rb    = id >> 3;                 // 0..127
    const int h     = (slot & 1) * 64 + (rb >> 1);
    const int whalf = rb & 1;
    const int w0    = whalf * 64;
    const int tid   = threadIdx.x;
    const int lane  = tid & 63;
    const int px    = tid & 63;
    const int wv    = __builtin_amdgcn_readfirstlane(tid >> 6);  // wave id

    __shared__ __align__(16) unsigned short xs[3 * 66 * SP];     // 28512 B

    // stage: 192 (ky,ci) pairs, one pair per wave-iteration, px = lane
#pragma unroll 4
    for (int it = 0; it < 48; it++) {
        int pair = it * 4 + wv;
        int ky = pair >> 6;                    // 0..2
        int ci = pair & 63;
        int hr = h - 1 + ky;
        bool rok = (unsigned)hr < HH;
        const float* base = x + (((size_t)b * CHI + ci) * HH + (rok ? hr : 0)) * WW;
        float v = rok ? base[w0 + px] : 0.f;   // pxpos = px+1  (wc = w0+px)
        xs[(ky * 66 + px + 1) * SP + ci] = f2bf(v);
        if (px < 2) {                          // halo: pxpos 0 and 65
            int p  = px * 65;
            int wc = w0 - 1 + p;
            float hv = (rok && (unsigned)wc < WW) ? base[wc] : 0.f;
            xs[(ky * 66 + p) * SP + ci] = f2bf(hv);
        }
    }
    __syncthreads();

    const int quad = lane >> 4, pxin = lane & 15;   // B: k=quad*8+j, n=pxin
    f32x4 acc0 = {0.f, 0.f, 0.f, 0.f};             // co 0..15
    f32x4 acc1 = {0.f, 0.f, 0.f, 0.f};             // co 16..26 (+pad)

#pragma unroll 3
    for (int kk = 0; kk < KK; kk++) {
        const int ky = kk / 3, kx = kk - ky * 3;
#pragma unroll
        for (int ks = 0; ks < 2; ks++) {
            const bf16x8* wa = (const bf16x8*)woA + (size_t)((kk * 2 + ks) * 2) * 64;
            bf16x8 A0 = wa[lane];
            bf16x8 A1 = wa[64 + lane];
            bf16x8 B = *(const bf16x8*)&xs[(ky * 66 + wv * 16 + pxin + kx) * SP
                                           + ks * 32 + quad * 8];
            acc0 = __builtin_amdgcn_mfma_f32_16x16x32_bf16(A0, B, acc0, 0, 0, 0);
            acc1 = __builtin_amdgcn_mfma_f32_16x16x32_bf16(A1, B, acc1, 0, 0, 0);
        }
    }

    // C layout: col(n=px)=lane&15, row(m=c)=(lane>>4)*4+reg
    float* outp = off + ((size_t)b * NOFF * HH + h) * WW + w0 + wv * 16 + pxin;
#pragma unroll
    for (int r = 0; r < 4; r++) {
        int c0 = quad * 4 + r;
        outp[c0 * PLANE] = acc0[r];
        int c1 = 16 + quad * 4 + r;
        if (c1 < NOFF) outp[c1 * PLANE] = acc1[r];
    }
}

// ---------------- deform sample + MFMA main conv ----------------
// R10 structure + explicit gather staging: all 32 loads of a kk live in
// q0[16]/q1[16] (64 VGPRs) BEFORE any convert -> one vmcnt drain per kk
// instead of ~16 (R10's VGPR=40 register-reuse serialization, 8.2 us/kk).
// Next-kk offsets prefetched; A-frags issued pre-barrier. Stats fused into
// the epilogue (width-16 shuffle reduce + atomics) - kills stats_kernel.
// grid 1024: blockIdx%8 -> (b, h-half) XCD swizzle.
__global__ __launch_bounds__(256, 4) void deform_kernel(const float* __restrict__ x,
                                                        const unsigned short* __restrict__ w_bf,
                                                        const float* __restrict__ off,
                                                        const float* __restrict__ b_off,
                                                        const float* __restrict__ bias,
                                                        float* __restrict__ out,
                                                        float* __restrict__ stats) {
    const int id    = blockIdx.x;
    const int slot  = id & 7;
    const int b     = slot >> 1;
    const int rb    = id >> 3;                 // 0..127
    const int h     = (slot & 1) * 64 + (rb >> 1);
    const int whalf = rb & 1;
    const int tid   = threadIdx.x;
    const int lane  = tid & 63;

    const int pxs      = tid & 63;
    const int cig      = __builtin_amdgcn_readfirstlane(tid >> 6);
    const int pxin_s   = pxs & 15, pxtile_s = pxs >> 4;
    const int wave  = cig;
    const int quadc = lane >> 4, pxinc = lane & 15;
    const int colc  = pxinc ^ quadc;

    __shared__ __align__(16) unsigned short vbuf[4096];
    bf16x8* vals = (bf16x8*)vbuf;

    f32x4 acc[4];
#pragma unroll
    for (int t = 0; t < 4; t++) acc[t] = (f32x4){0.f, 0.f, 0.f, 0.f};

    const float* xb   = x + ((size_t)b * CHI + cig * 16) * PLANE;
    const float* offb = off + (size_t)b * NOFF * PLANE + h * WW + whalf * 64 + pxs;
    const int w = whalf * 64 + pxs;

    // prologue: kk=0 raw offsets
    float dy = offb[0];
    float dx = offb[PLANE];
    float mo = offb[18 * PLANE];

#pragma unroll 1
    for (int kk = 0; kk < KK; kk++) {
        const int ky = kk / 3, kx = kk % 3;
        float cdy = dy + b_off[2 * kk];
        float cdx = dx + b_off[2 * kk + 1];
        float cmo = mo + b_off[18 + kk];
        float m  = 1.f / (1.f + __expf(-cmo));

        float py = (float)(h - 1 + ky) + cdy;
        float px_ = (float)(w - 1 + kx) + cdx;
        float fy0 = floorf(py), fx0 = floorf(px_);
        float wy = py - fy0, wx = px_ - fx0;
        int y0 = (int)fy0, x0 = (int)fx0;
        int y1 = y0 + 1, x1 = x0 + 1;
        bool vy0 = (unsigned)y0 < HH, vy1 = (unsigned)y1 < HH;
        bool vx0 = (unsigned)x0 < WW, vx1 = (unsigned)x1 < WW;
        float a00 = (vy0 && vx0) ? (1.f - wy) * (1.f - wx) * m : 0.f;
        float a01 = (vy0 && vx1) ? (1.f - wy) * wx * m : 0.f;
        float a10 = (vy1 && vx0) ? wy * (1.f - wx) * m : 0.f;
        float a11 = (vy1 && vx1) ? wy * wx * m : 0.f;

        int xbc = min(max(x0, 0), WW - 2);
        bool sel = (x0 == xbc);
        v2f cA = { sel ? a00 : a01, sel ? a01 : a00 };
        v2f cB = { sel ? a10 : a11, sel ? a11 : a10 };
        int cy0 = min(max(y0, 0), HH - 1), cy1 = min(max(y1, 0), HH - 1);
        const unsigned o0 = (unsigned)(cy0 * WW + xbc);
        const unsigned o1 = (unsigned)(cy1 * WW + xbc);

        // ---- stage ALL 32 gathers (in flight together) ----
        f2v q0[16], q1[16];
        {
            const float* pl = xb;
#pragma unroll
            for (int ci = 0; ci < 16; ci++) {
                q0[ci] = *(const f2v*)(pl + o0);
                q1[ci] = *(const f2v*)(pl + o1);
                pl += PLANE;
            }
        }
        // prefetch next kk's raw offsets (younger loads; convert won't wait on them)
        if (kk < 8) {
            dy = offb[(2 * kk + 2) * PLANE];
            dx = offb[(2 * kk + 3) * PLANE];
            mo = offb[(19 + kk) * PLANE];
        }

        // ---- convert -> bf16 fragments -> LDS ----
#pragma unroll
        for (int gg = 0; gg < 2; gg++) {
            bf16x8 tmp;
#pragma unroll
            for (int j = 0; j < 8; j++) {
                v2f t = pkfma((v2f)q1[gg * 8 + j], cB, (v2f)q0[gg * 8 + j] * cA);
                tmp[j] = (short)f2bf(t.x + t.y);
            }
            int quad = ((cig & 1) << 1) | gg;
            int ks   = cig >> 1;
            vals[(pxtile_s * 2 + ks) * 64 + (quad << 4) + (pxin_s ^ quad)] = tmp;
        }

        // A-fragments issued pre-barrier: latency hides under the sync
        const bf16x8* wb = (const bf16x8*)w_bf + (size_t)((kk * 4 + wave) * 2) * 64;
        bf16x8 A0 = wb[lane];
        bf16x8 A1 = wb[64 + lane];
        __syncthreads();

#pragma unroll
        for (int t = 0; t < 4; t++) {
            bf16x8 B0 = vals[(t * 2 + 0) * 64 + (quadc << 4) + colc];
            bf16x8 B1 = vals[(t * 2 + 1) * 64 + (quadc << 4) + colc];
            acc[t] = __builtin_amdgcn_mfma_f32_16x16x32_bf16(A0, B0, acc[t], 0, 0, 0);
            acc[t] = __builtin_amdgcn_mfma_f32_16x16x32_bf16(A1, B1, acc[t], 0, 0, 0);
        }
        __syncthreads();
    }

    // epilogue: write out + fused per-channel stats
    // C/D layout: col(n=px)=lane&15, row(m=co)=(lane>>4)*4+reg
    float bi[4], sum_r[4], ssq_r[4];
#pragma unroll
    for (int r = 0; r < 4; r++) {
        bi[r] = bias[wave * 16 + quadc * 4 + r];
        sum_r[r] = 0.f;
        ssq_r[r] = 0.f;
    }
#pragma unroll
    for (int t = 0; t < 4; t++) {
#pragma unroll
        for (int r = 0; r < 4; r++) {
            int co = wave * 16 + quadc * 4 + r;
            float val = acc[t][r] + bi[r];
            out[(((size_t)b * CHO + co) * HH + h) * WW + whalf * 64 + t * 16 + pxinc] = val;
            sum_r[r] += val;
            ssq_r[r] += val * val;
        }
    }
    // reduce across the 16 lanes sharing (wave, quadc) -> one partial per co
#pragma unroll
    for (int r = 0; r < 4; r++) {
#pragma unroll
        for (int o = 8; o > 0; o >>= 1) {
            sum_r[r] += __shfl_down(sum_r[r], o, 16);
            ssq_r[r] += __shfl_down(ssq_r[r], o, 16);
        }
    }
    if (pxinc == 0) {
#pragma unroll
        for (int r = 0; r < 4; r++) {
            int co = wave * 16 + quadc * 4 + r;
            atomicAdd(&stats[co], sum_r[r]);
            atomicAdd(&stats[64 + co], ssq_r[r]);
        }
    }
}

// ---------------- BN + ReLU, in place on d_out ----------------
__global__ __launch_bounds__(256) void bn_kernel(float* __restrict__ y,
                                                 const float* __restrict__ stats,
                                                 const float* __restrict__ gamma,
                                                 const float* __restrict__ beta) {
    size_t base = (size_t)blockIdx.x * 1024;
    int co = (int)((base >> 14) & 63);
    const float inv_n = 1.f / 65536.f;
    float mean = stats[co] * inv_n;
    float var  = stats[64 + co] * inv_n - mean * mean;
    float sc = gamma[co] * rsqrtf(var + EPSV);
    float sh = beta[co] - mean * sc;
    float4* p = (float4*)(y + base);
    float4 v = p[threadIdx.x];
    v.x = fmaxf(fmaf(v.x, sc, sh), 0.f);
    v.y = fmaxf(fmaf(v.y, sc, sh), 0.f);
    v.z = fmaxf(fmaf(v.z, sc, sh), 0.f);
    v.w = fmaxf(fmaf(v.w, sc, sh), 0.f);
    p[threadIdx.x] = v;
}

extern "C" void kernel_launch(void* const* d_in, const int* in_sizes, int n_in,
                              void* d_out, int out_size, void* d_ws, size_t ws_size,
                              hipStream_t stream) {
    const float* x     = (const float*)d_in[0];
    const float* w_off = (const float*)d_in[1];
    const float* b_off = (const float*)d_in[2];
    const float* wmat  = (const float*)d_in[3];
    const float* bvec  = (const float*)d_in[4];
    const float* gamma = (const float*)d_in[5];
    const float* beta  = (const float*)d_in[6];
    float* out = (float*)d_out;

    char* ws = (char*)d_ws;
    float* stats          = (float*)ws;                   // 512 B
    unsigned short* w_bf  = (unsigned short*)(ws + 1024); // 73728 B
    unsigned short* woA   = (unsigned short*)(ws + 74752);// 36864 B
    float* off            = (float*)(ws + 139264);        // 7077888 B

    hipMemsetAsync(stats, 0, 512, stream);
    prep_kernel<<<144, 256, 0, stream>>>(wmat, w_off, w_bf, woA);
    off_conv_kernel<<<1024, 256, 0, stream>>>(x, woA, off);
    deform_kernel<<<1024, 256, 0, stream>>>(x, w_bf, off, b_off, bvec, out, stats);
    bn_kernel<<<4096, 256, 0, stream>>>(out, stats, gamma, beta);
}

// Round 12
// 246.474 us; speedup vs baseline: 1.0254x; 1.0254x over previous
//
#include <hip/hip_runtime.h>
#include <math.h>

#define CHI 64
#define CHO 64
#define HH 128
#define WW 128
#define NB 4
#define KK 9
#define NOFF 27
#define EPSV 1e-5f
#define PLANE (HH * WW)
#define SP 72                 // LDS ci-stride (bytes=144: 16B-aligned, uniform banks)

typedef float v2f __attribute__((ext_vector_type(2)));
typedef float f2v __attribute__((ext_vector_type(2), aligned(4)));
typedef float f32x4 __attribute__((ext_vector_type(4)));
typedef short bf16x8 __attribute__((ext_vector_type(8)));

__device__ __forceinline__ v2f pkfma(v2f a, v2f b, v2f c) {
#if __has_builtin(__builtin_elementwise_fma)
    return __builtin_elementwise_fma(a, b, c);
#else
    return a * b + c;
#endif
}

// fp32 -> bf16 round-to-nearest-even
__device__ __forceinline__ unsigned short f2bf(float f) {
    unsigned u = __float_as_uint(f);
    u += 0x7fff + ((u >> 16) & 1);
    return (unsigned short)(u >> 16);
}

// ---------------- prep: pack MFMA A-fragment tables (bf16) ----------------
// A-frag layout (mfma_f32_16x16x32_bf16): lane holds A[m=lane&15][k=(lane>>4)*8+j]
// w_bf  (deform):  elem = (((kk*4+ct)*2+ks)*64 + lane)*8 + j ; co=ct*16+m, ci=ks*32+k
// woA (off_conv):  elem = (((kk*2+ks)*2+ct)*64 + lane)*8 + j ; c =ct*16+m (0 if >=27)
__global__ __launch_bounds__(256) void prep_kernel(const float* __restrict__ w,
                                                   const float* __restrict__ w_off,
                                                   unsigned short* __restrict__ w_bf,
                                                   unsigned short* __restrict__ woA) {
    int i = blockIdx.x * 256 + threadIdx.x;    // grid 144*256 = 36864 exactly
    {
        int j    = i & 7;
        int lane = (i >> 3) & 63;
        int ks   = (i >> 9) & 1;
        int ct   = (i >> 10) & 3;
        int kk   = i >> 12;                    // 0..8
        int co   = ct * 16 + (lane & 15);
        int ci   = ks * 32 + ((lane >> 4) & 3) * 8 + j;
        w_bf[i]  = f2bf(w[(co * CHI + ci) * KK + kk]);
    }
    if (i < 18432) {
        int j    = i & 7;
        int lane = (i >> 3) & 63;
        int ct   = (i >> 9) & 1;
        int ks   = (i >> 10) & 1;
        int kk   = i >> 11;                    // 0..8
        int c    = ct * 16 + (lane & 15);
        int ci   = ks * 32 + (lane >> 4) * 8 + j;
        woA[i]   = (c < NOFF) ? f2bf(w_off[(c * CHI + ci) * KK + kk]) : (unsigned short)0;
    }
}

// ---------------- offset conv via MFMA ----------------
// Block 256 = 4 waves, half-row (64 px) x all 27 co. Stage x window
// (3 rows x 66 px x 64 ci) as bf16 in LDS via float4 loads (4 px/lane,
// 12 wave-iters instead of 48 scalar), halo hoisted out of the hot loop.
// Then 9 taps x K=64 MFMA with prepacked A-fragments (no s_load chain).
// grid 1024: blockIdx%8 -> (b, h-half) XCD swizzle.
__global__ __launch_bounds__(256) void off_conv_kernel(const float* __restrict__ x,
                                                       const unsigned short* __restrict__ woA,
                                                       float* __restrict__ off) {
    const int id    = blockIdx.x;
    const int slot  = id & 7;
    const int b     = slot >> 1;
    const int rb    = id >> 3;                 // 0..127
    const int h     = (slot & 1) * 64 + (rb >> 1);
    const int whalf = rb & 1;
    const int w0    = whalf * 64;
    const int tid   = threadIdx.x;
    const int lane  = tid & 63;
    const int wv    = __builtin_amdgcn_readfirstlane(tid >> 6);  // wave id

    __shared__ __align__(16) unsigned short xs[3 * 66 * SP];     // 28512 B

    // interior staging: lane -> 4 px (float4), wave-iter -> (ky, 4-ci group)
    {
        const int px4 = (lane & 15) * 4;
        const int cio = lane >> 4;
#pragma unroll 3
        for (int it = 0; it < 12; it++) {
            int g  = it * 4 + wv;              // 0..47
            int ky = g >> 4;                   // 0..2
            int ci = (g & 15) * 4 + cio;
            int hr = h - 1 + ky;
            bool rok = (unsigned)hr < HH;
            const float* base = x + (((size_t)b * CHI + ci) * HH + (rok ? hr : 0)) * WW + w0 + px4;
            float4 v = rok ? *(const float4*)base : make_float4(0.f, 0.f, 0.f, 0.f);
            unsigned short* d = &xs[(ky * 66 + px4 + 1) * SP + ci];
            d[0]        = f2bf(v.x);
            d[SP]       = f2bf(v.y);
            d[2 * SP]   = f2bf(v.z);
            d[3 * SP]   = f2bf(v.w);
        }
    }
    // halo: pxpos 0 (wc=w0-1) and 65 (wc=w0+64); 384 values
    for (int t = tid; t < 384; t += 256) {
        int ky = t >> 7, ci = (t >> 1) & 63, side = t & 1;
        int hr = h - 1 + ky;
        int wc = w0 - 1 + side * 65;
        bool ok = ((unsigned)hr < HH) && ((unsigned)wc < WW);
        float v = ok ? x[(((size_t)b * CHI + ci) * HH + (ok ? hr : 0)) * WW + (ok ? wc : 0)] : 0.f;
        xs[(ky * 66 + side * 65) * SP + ci] = f2bf(v);
    }
    __syncthreads();

    const int quad = lane >> 4, pxin = lane & 15;   // B: k=quad*8+j, n=pxin
    f32x4 acc0 = {0.f, 0.f, 0.f, 0.f};             // co 0..15
    f32x4 acc1 = {0.f, 0.f, 0.f, 0.f};             // co 16..26 (+pad)

#pragma unroll 3
    for (int kk = 0; kk < KK; kk++) {
        const int ky = kk / 3, kx = kk - ky * 3;
#pragma unroll
        for (int ks = 0; ks < 2; ks++) {
            const bf16x8* wa = (const bf16x8*)woA + (size_t)((kk * 2 + ks) * 2) * 64;
            bf16x8 A0 = wa[lane];
            bf16x8 A1 = wa[64 + lane];
            bf16x8 B = *(const bf16x8*)&xs[(ky * 66 + wv * 16 + pxin + kx) * SP
                                           + ks * 32 + quad * 8];
            acc0 = __builtin_amdgcn_mfma_f32_16x16x32_bf16(A0, B, acc0, 0, 0, 0);
            acc1 = __builtin_amdgcn_mfma_f32_16x16x32_bf16(A1, B, acc1, 0, 0, 0);
        }
    }

    // C layout: col(n=px)=lane&15, row(m=c)=(lane>>4)*4+reg
    float* outp = off + ((size_t)b * NOFF * HH + h) * WW + w0 + wv * 16 + pxin;
#pragma unroll
    for (int r = 0; r < 4; r++) {
        int c0 = quad * 4 + r;
        outp[c0 * PLANE] = acc0[r];
        int c1 = 16 + quad * 4 + r;
        if (c1 < NOFF) outp[c1 * PLANE] = acc1[r];
    }
}

// ---------------- deform sample + MFMA main conv ----------------
// EXACT R10 main loop (proven 74 us; R11's hand-staging regressed it — the
// compiler's own gather scheduling at VGPR=40 wins). Only change: fused
// per-channel stats in the epilogue (width-16 shuffle + atomics).
// grid 1024: blockIdx%8 -> (b, h-half) XCD swizzle.
__global__ __launch_bounds__(256, 2) void deform_kernel(const float* __restrict__ x,
                                                        const unsigned short* __restrict__ w_bf,
                                                        const float* __restrict__ off,
                                                        const float* __restrict__ b_off,
                                                        const float* __restrict__ bias,
                                                        float* __restrict__ out,
                                                        float* __restrict__ stats) {
    const int id    = blockIdx.x;
    const int slot  = id & 7;
    const int b     = slot >> 1;
    const int rb    = id >> 3;                 // 0..127
    const int h     = (slot & 1) * 64 + (rb >> 1);
    const int whalf = rb & 1;
    const int tid   = threadIdx.x;
    const int lane  = tid & 63;

    const int pxs      = tid & 63;
    const int cig      = __builtin_amdgcn_readfirstlane(tid >> 6);
    const int pxin_s   = pxs & 15, pxtile_s = pxs >> 4;
    const int wave  = cig;
    const int quadc = lane >> 4, pxinc = lane & 15;
    const int colc  = pxinc ^ quadc;

    __shared__ __align__(16) unsigned short vbuf[4096];
    bf16x8* vals = (bf16x8*)vbuf;

    f32x4 acc[4];
#pragma unroll
    for (int t = 0; t < 4; t++) acc[t] = (f32x4){0.f, 0.f, 0.f, 0.f};

    const float* xb   = x + ((size_t)b * CHI + cig * 16) * PLANE;
    const float* offb = off + (size_t)b * NOFF * PLANE + h * WW + whalf * 64 + pxs;
    const int w = whalf * 64 + pxs;

#pragma unroll 1
    for (int kk = 0; kk < KK; kk++) {
        const int ky = kk / 3, kx = kk % 3;
        float dy = offb[(2 * kk) * PLANE]     + b_off[2 * kk];
        float dx = offb[(2 * kk + 1) * PLANE] + b_off[2 * kk + 1];
        float mo = offb[(18 + kk) * PLANE]    + b_off[18 + kk];
        float m  = 1.f / (1.f + __expf(-mo));

        float py = (float)(h - 1 + ky) + dy;
        float px_ = (float)(w - 1 + kx) + dx;
        float fy0 = floorf(py), fx0 = floorf(px_);
        float wy = py - fy0, wx = px_ - fx0;
        int y0 = (int)fy0, x0 = (int)fx0;
        int y1 = y0 + 1, x1 = x0 + 1;
        bool vy0 = (unsigned)y0 < HH, vy1 = (unsigned)y1 < HH;
        bool vx0 = (unsigned)x0 < WW, vx1 = (unsigned)x1 < WW;
        float a00 = (vy0 && vx0) ? (1.f - wy) * (1.f - wx) * m : 0.f;
        float a01 = (vy0 && vx1) ? (1.f - wy) * wx * m : 0.f;
        float a10 = (vy1 && vx0) ? wy * (1.f - wx) * m : 0.f;
        float a11 = (vy1 && vx1) ? wy * wx * m : 0.f;

        int xbc = min(max(x0, 0), WW - 2);
        bool sel = (x0 == xbc);
        v2f cA = { sel ? a00 : a01, sel ? a01 : a00 };
        v2f cB = { sel ? a10 : a11, sel ? a11 : a10 };
        int cy0 = min(max(y0, 0), HH - 1), cy1 = min(max(y1, 0), HH - 1);
        const unsigned o0 = (unsigned)(cy0 * WW + xbc);
        const unsigned o1 = (unsigned)(cy1 * WW + xbc);

        const float* pl = xb;
#pragma unroll
        for (int gg = 0; gg < 2; gg++) {
            bf16x8 tmp;
#pragma unroll
            for (int j = 0; j < 8; j++) {
                f2v p0 = *(const f2v*)(pl + o0);
                f2v p1 = *(const f2v*)(pl + o1);
                v2f t = pkfma((v2f)p1, cB, (v2f)p0 * cA);
                tmp[j] = (short)f2bf(t.x + t.y);
                pl += PLANE;
            }
            int quad = ((cig & 1) << 1) | gg;
            int ks   = cig >> 1;
            vals[(pxtile_s * 2 + ks) * 64 + (quad << 4) + (pxin_s ^ quad)] = tmp;
        }
        __syncthreads();

        const bf16x8* wb = (const bf16x8*)w_bf + (size_t)((kk * 4 + wave) * 2) * 64;
        bf16x8 A0 = wb[lane];
        bf16x8 A1 = wb[64 + lane];
#pragma unroll
        for (int t = 0; t < 4; t++) {
            bf16x8 B0 = vals[(t * 2 + 0) * 64 + (quadc << 4) + colc];
            bf16x8 B1 = vals[(t * 2 + 1) * 64 + (quadc << 4) + colc];
            acc[t] = __builtin_amdgcn_mfma_f32_16x16x32_bf16(A0, B0, acc[t], 0, 0, 0);
            acc[t] = __builtin_amdgcn_mfma_f32_16x16x32_bf16(A1, B1, acc[t], 0, 0, 0);
        }
        __syncthreads();
    }

    // epilogue: write out + fused per-channel stats
    // C/D layout: col(n=px)=lane&15, row(m=co)=(lane>>4)*4+reg
    float bi[4], sum_r[4], ssq_r[4];
#pragma unroll
    for (int r = 0; r < 4; r++) {
        bi[r] = bias[wave * 16 + quadc * 4 + r];
        sum_r[r] = 0.f;
        ssq_r[r] = 0.f;
    }
#pragma unroll
    for (int t = 0; t < 4; t++) {
#pragma unroll
        for (int r = 0; r < 4; r++) {
            int co = wave * 16 + quadc * 4 + r;
            float val = acc[t][r] + bi[r];
            out[(((size_t)b * CHO + co) * HH + h) * WW + whalf * 64 + t * 16 + pxinc] = val;
            sum_r[r] += val;
            ssq_r[r] += val * val;
        }
    }
    // reduce across the 16 lanes sharing (wave, quadc) -> one partial per co
#pragma unroll
    for (int r = 0; r < 4; r++) {
#pragma unroll
        for (int o = 8; o > 0; o >>= 1) {
            sum_r[r] += __shfl_down(sum_r[r], o, 16);
            ssq_r[r] += __shfl_down(ssq_r[r], o, 16);
        }
    }
    if (pxinc == 0) {
#pragma unroll
        for (int r = 0; r < 4; r++) {
            int co = wave * 16 + quadc * 4 + r;
            atomicAdd(&stats[co], sum_r[r]);
            atomicAdd(&stats[64 + co], ssq_r[r]);
        }
    }
}

// ---------------- BN + ReLU, in place on d_out ----------------
__global__ __launch_bounds__(256) void bn_kernel(float* __restrict__ y,
                                                 const float* __restrict__ stats,
                                                 const float* __restrict__ gamma,
                                                 const float* __restrict__ beta) {
    size_t base = (size_t)blockIdx.x * 1024;
    int co = (int)((base >> 14) & 63);
    const float inv_n = 1.f / 65536.f;
    float mean = stats[co] * inv_n;
    float var  = stats[64 + co] * inv_n - mean * mean;
    float sc = gamma[co] * rsqrtf(var + EPSV);
    float sh = beta[co] - mean * sc;
    float4* p = (float4*)(y + base);
    float4 v = p[threadIdx.x];
    v.x = fmaxf(fmaf(v.x, sc, sh), 0.f);
    v.y = fmaxf(fmaf(v.y, sc, sh), 0.f);
    v.z = fmaxf(fmaf(v.z, sc, sh), 0.f);
    v.w = fmaxf(fmaf(v.w, sc, sh), 0.f);
    p[threadIdx.x] = v;
}

extern "C" void kernel_launch(void* const* d_in, const int* in_sizes, int n_in,
                              void* d_out, int out_size, void* d_ws, size_t ws_size,
                              hipStream_t stream) {
    const float* x     = (const float*)d_in[0];
    const float* w_off = (const float*)d_in[1];
    const float* b_off = (const float*)d_in[2];
    const float* wmat  = (const float*)d_in[3];
    const float* bvec  = (const float*)d_in[4];
    const float* gamma = (const float*)d_in[5];
    const float* beta  = (const float*)d_in[6];
    float* out = (float*)d_out;

    char* ws = (char*)d_ws;
    float* stats          = (float*)ws;                   // 512 B
    unsigned short* w_bf  = (unsigned short*)(ws + 1024); // 73728 B
    unsigned short* woA   = (unsigned short*)(ws + 74752);// 36864 B
    float* off            = (float*)(ws + 139264);        // 7077888 B

    hipMemsetAsync(stats, 0, 512, stream);
    prep_kernel<<<144, 256, 0, stream>>>(wmat, w_off, w_bf, woA);
    off_conv_kernel<<<1024, 256, 0, stream>>>(x, woA, off);
    deform_kernel<<<1024, 256, 0, stream>>>(x, w_bf, off, b_off, bvec, out, stats);
    bn_kernel<<<4096, 256, 0, stream>>>(out, stats, gamma, beta);
}

// Round 13
// 186.350 us; speedup vs baseline: 1.3562x; 1.3226x over previous
//
#include <hip/hip_runtime.h>
#include <math.h>

#define CHI 64
#define CHO 64
#define HH 128
#define WW 128
#define NB 4
#define KK 9
#define NOFF 27
#define EPSV 1e-5f
#define PLANE (HH * WW)
#define SP 72                 // LDS ci-stride (bytes=144: 16B-aligned, b128 2-way=free)

typedef float v2f __attribute__((ext_vector_type(2)));
typedef float f2v __attribute__((ext_vector_type(2), aligned(4)));
typedef float f32x4 __attribute__((ext_vector_type(4)));
typedef short bf16x8 __attribute__((ext_vector_type(8)));

__device__ __forceinline__ v2f pkfma(v2f a, v2f b, v2f c) {
#if __has_builtin(__builtin_elementwise_fma)
    return __builtin_elementwise_fma(a, b, c);
#else
    return a * b + c;
#endif
}

// fp32 -> bf16 round-to-nearest-even
__device__ __forceinline__ unsigned short f2bf(float f) {
    unsigned u = __float_as_uint(f);
    u += 0x7fff + ((u >> 16) & 1);
    return (unsigned short)(u >> 16);
}

// ---------------- prep: pack MFMA A-fragment tables (bf16) ----------------
__global__ __launch_bounds__(256) void prep_kernel(const float* __restrict__ w,
                                                   const float* __restrict__ w_off,
                                                   unsigned short* __restrict__ w_bf,
                                                   unsigned short* __restrict__ woA) {
    int i = blockIdx.x * 256 + threadIdx.x;    // grid 144*256 = 36864 exactly
    {
        int j    = i & 7;
        int lane = (i >> 3) & 63;
        int ks   = (i >> 9) & 1;
        int ct   = (i >> 10) & 3;
        int kk   = i >> 12;                    // 0..8
        int co   = ct * 16 + (lane & 15);
        int ci   = ks * 32 + ((lane >> 4) & 3) * 8 + j;
        w_bf[i]  = f2bf(w[(co * CHI + ci) * KK + kk]);
    }
    if (i < 18432) {
        int j    = i & 7;
        int lane = (i >> 3) & 63;
        int ct   = (i >> 9) & 1;
        int ks   = (i >> 10) & 1;
        int kk   = i >> 11;                    // 0..8
        int c    = ct * 16 + (lane & 15);
        int ci   = ks * 32 + (lane >> 4) * 8 + j;
        woA[i]   = (c < NOFF) ? f2bf(w_off[(c * CHI + ci) * KK + kk]) : (unsigned short)0;
    }
}

// ---------------- offset conv via MFMA (unchanged from R12) ----------------
__global__ __launch_bounds__(256) void off_conv_kernel(const float* __restrict__ x,
                                                       const unsigned short* __restrict__ woA,
                                                       float* __restrict__ off) {
    const int id    = blockIdx.x;
    const int slot  = id & 7;
    const int b     = slot >> 1;
    const int rb    = id >> 3;                 // 0..127
    const int h     = (slot & 1) * 64 + (rb >> 1);
    const int whalf = rb & 1;
    const int w0    = whalf * 64;
    const int tid   = threadIdx.x;
    const int lane  = tid & 63;
    const int wv    = __builtin_amdgcn_readfirstlane(tid >> 6);

    __shared__ __align__(16) unsigned short xs[3 * 66 * SP];     // 28512 B

    {
        const int px4 = (lane & 15) * 4;
        const int cio = lane >> 4;
#pragma unroll 3
        for (int it = 0; it < 12; it++) {
            int g  = it * 4 + wv;              // 0..47
            int ky = g >> 4;
            int ci = (g & 15) * 4 + cio;
            int hr = h - 1 + ky;
            bool rok = (unsigned)hr < HH;
            const float* base = x + (((size_t)b * CHI + ci) * HH + (rok ? hr : 0)) * WW + w0 + px4;
            float4 v = rok ? *(const float4*)base : make_float4(0.f, 0.f, 0.f, 0.f);
            unsigned short* d = &xs[(ky * 66 + px4 + 1) * SP + ci];
            d[0]        = f2bf(v.x);
            d[SP]       = f2bf(v.y);
            d[2 * SP]   = f2bf(v.z);
            d[3 * SP]   = f2bf(v.w);
        }
    }
    for (int t = tid; t < 384; t += 256) {
        int ky = t >> 7, ci = (t >> 1) & 63, side = t & 1;
        int hr = h - 1 + ky;
        int wc = w0 - 1 + side * 65;
        bool ok = ((unsigned)hr < HH) && ((unsigned)wc < WW);
        float v = ok ? x[(((size_t)b * CHI + ci) * HH + (ok ? hr : 0)) * WW + (ok ? wc : 0)] : 0.f;
        xs[(ky * 66 + side * 65) * SP + ci] = f2bf(v);
    }
    __syncthreads();

    const int quad = lane >> 4, pxin = lane & 15;
    f32x4 acc0 = {0.f, 0.f, 0.f, 0.f};
    f32x4 acc1 = {0.f, 0.f, 0.f, 0.f};

#pragma unroll 3
    for (int kk = 0; kk < KK; kk++) {
        const int ky = kk / 3, kx = kk - ky * 3;
#pragma unroll
        for (int ks = 0; ks < 2; ks++) {
            const bf16x8* wa = (const bf16x8*)woA + (size_t)((kk * 2 + ks) * 2) * 64;
            bf16x8 A0 = wa[lane];
            bf16x8 A1 = wa[64 + lane];
            bf16x8 B = *(const bf16x8*)&xs[(ky * 66 + wv * 16 + pxin + kx) * SP
                                           + ks * 32 + quad * 8];
            acc0 = __builtin_amdgcn_mfma_f32_16x16x32_bf16(A0, B, acc0, 0, 0, 0);
            acc1 = __builtin_amdgcn_mfma_f32_16x16x32_bf16(A1, B, acc1, 0, 0, 0);
        }
    }

    float* outp = off + ((size_t)b * NOFF * HH + h) * WW + w0 + wv * 16 + pxin;
#pragma unroll
    for (int r = 0; r < 4; r++) {
        int c0 = quad * 4 + r;
        outp[c0 * PLANE] = acc0[r];
        int c1 = 16 + quad * 4 + r;
        if (c1 < NOFF) outp[c1 * PLANE] = acc1[r];
    }
}

// ---------------- deform sample + MFMA main conv ----------------
// R10-exact main loop (proven 74 us). kk-range split across 2 blocks when
// `split`!=0 (grid 2048 -> 8 blocks/CU vs 4: deform was grid-limited).
// v=0: kk 0..3 -> part0 ; v=1: kk 4..8 -> out. Bias deferred to stats/bn.
// NO fused stats (R12 lesson: 131k cross-XCD same-line atomics = +80 us).
__global__ __launch_bounds__(256, 2) void deform_kernel(const float* __restrict__ x,
                                                        const unsigned short* __restrict__ w_bf,
                                                        const float* __restrict__ off,
                                                        const float* __restrict__ b_off,
                                                        float* __restrict__ out,
                                                        float* __restrict__ part0,
                                                        int split) {
    const int id    = blockIdx.x;
    const int slot  = id & 7;
    const int b     = slot >> 1;
    int rb, klo, khi;
    float* dest;
    if (split) {
        int v = (id >> 3) & 1;
        rb  = id >> 4;                         // 0..127
        klo = v ? 4 : 0;
        khi = v ? 9 : 4;
        dest = v ? out : part0;
    } else {
        rb  = id >> 3;
        klo = 0; khi = 9;
        dest = out;
    }
    const int h     = (slot & 1) * 64 + (rb >> 1);
    const int whalf = rb & 1;
    const int tid   = threadIdx.x;
    const int lane  = tid & 63;

    const int pxs      = tid & 63;
    const int cig      = __builtin_amdgcn_readfirstlane(tid >> 6);
    const int pxin_s   = pxs & 15, pxtile_s = pxs >> 4;
    const int wave  = cig;
    const int quadc = lane >> 4, pxinc = lane & 15;
    const int colc  = pxinc ^ quadc;

    __shared__ __align__(16) unsigned short vbuf[4096];
    bf16x8* vals = (bf16x8*)vbuf;

    f32x4 acc[4];
#pragma unroll
    for (int t = 0; t < 4; t++) acc[t] = (f32x4){0.f, 0.f, 0.f, 0.f};

    const float* xb   = x + ((size_t)b * CHI + cig * 16) * PLANE;
    const float* offb = off + (size_t)b * NOFF * PLANE + h * WW + whalf * 64 + pxs;
    const int w = whalf * 64 + pxs;

#pragma unroll 1
    for (int kk = klo; kk < khi; kk++) {
        const int ky = kk / 3, kx = kk % 3;
        float dy = offb[(2 * kk) * PLANE]     + b_off[2 * kk];
        float dx = offb[(2 * kk + 1) * PLANE] + b_off[2 * kk + 1];
        float mo = offb[(18 + kk) * PLANE]    + b_off[18 + kk];
        float m  = 1.f / (1.f + __expf(-mo));

        float py = (float)(h - 1 + ky) + dy;
        float px_ = (float)(w - 1 + kx) + dx;
        float fy0 = floorf(py), fx0 = floorf(px_);
        float wy = py - fy0, wx = px_ - fx0;
        int y0 = (int)fy0, x0 = (int)fx0;
        int y1 = y0 + 1, x1 = x0 + 1;
        bool vy0 = (unsigned)y0 < HH, vy1 = (unsigned)y1 < HH;
        bool vx0 = (unsigned)x0 < WW, vx1 = (unsigned)x1 < WW;
        float a00 = (vy0 && vx0) ? (1.f - wy) * (1.f - wx) * m : 0.f;
        float a01 = (vy0 && vx1) ? (1.f - wy) * wx * m : 0.f;
        float a10 = (vy1 && vx0) ? wy * (1.f - wx) * m : 0.f;
        float a11 = (vy1 && vx1) ? wy * wx * m : 0.f;

        int xbc = min(max(x0, 0), WW - 2);
        bool sel = (x0 == xbc);
        v2f cA = { sel ? a00 : a01, sel ? a01 : a00 };
        v2f cB = { sel ? a10 : a11, sel ? a11 : a10 };
        int cy0 = min(max(y0, 0), HH - 1), cy1 = min(max(y1, 0), HH - 1);
        const unsigned o0 = (unsigned)(cy0 * WW + xbc);
        const unsigned o1 = (unsigned)(cy1 * WW + xbc);

        const float* pl = xb;
#pragma unroll
        for (int gg = 0; gg < 2; gg++) {
            bf16x8 tmp;
#pragma unroll
            for (int j = 0; j < 8; j++) {
                f2v p0 = *(const f2v*)(pl + o0);
                f2v p1 = *(const f2v*)(pl + o1);
                v2f t = pkfma((v2f)p1, cB, (v2f)p0 * cA);
                tmp[j] = (short)f2bf(t.x + t.y);
                pl += PLANE;
            }
            int quad = ((cig & 1) << 1) | gg;
            int ks   = cig >> 1;
            vals[(pxtile_s * 2 + ks) * 64 + (quad << 4) + (pxin_s ^ quad)] = tmp;
        }
        __syncthreads();

        const bf16x8* wb = (const bf16x8*)w_bf + (size_t)((kk * 4 + wave) * 2) * 64;
        bf16x8 A0 = wb[lane];
        bf16x8 A1 = wb[64 + lane];
#pragma unroll
        for (int t = 0; t < 4; t++) {
            bf16x8 B0 = vals[(t * 2 + 0) * 64 + (quadc << 4) + colc];
            bf16x8 B1 = vals[(t * 2 + 1) * 64 + (quadc << 4) + colc];
            acc[t] = __builtin_amdgcn_mfma_f32_16x16x32_bf16(A0, B0, acc[t], 0, 0, 0);
            acc[t] = __builtin_amdgcn_mfma_f32_16x16x32_bf16(A1, B1, acc[t], 0, 0, 0);
        }
        __syncthreads();
    }

    // epilogue: raw partial write (bias deferred to stats/bn)
#pragma unroll
    for (int t = 0; t < 4; t++) {
#pragma unroll
        for (int r = 0; r < 4; r++) {
            int co = wave * 16 + quadc * 4 + r;
            dest[(((size_t)b * CHO + co) * HH + h) * WW + whalf * 64 + t * 16 + pxinc] =
                acc[t][r];
        }
    }
}

// ---------------- per-channel stats: y = part0 + out(+bias) ----------------
// grid 1024: (co, b, seg). 2 atomics per block (4096 total, no hot-line storm).
__global__ __launch_bounds__(256) void stats_kernel(const float* __restrict__ y1,
                                                    const float* __restrict__ part0,
                                                    const float* __restrict__ bias,
                                                    float* __restrict__ stats,
                                                    int split) {
    const int co  = blockIdx.x & 63;
    const int b   = (blockIdx.x >> 6) & 3;
    const int seg = blockIdx.x >> 8;           // 0..3
    const size_t base = ((size_t)b * CHO + co) * PLANE + seg * (PLANE / 4);
    const float bi = bias[co];
    const float4* p1 = (const float4*)(y1 + base);
    const float4* p0 = (const float4*)(part0 + base);
    float s = 0.f, s2 = 0.f;
    for (int i = threadIdx.x; i < PLANE / 16; i += 256) {
        float4 v = p1[i];
        if (split) {
            float4 u = p0[i];
            v.x += u.x; v.y += u.y; v.z += u.z; v.w += u.w;
        }
        v.x += bi; v.y += bi; v.z += bi; v.w += bi;
        s  += v.x + v.y + v.z + v.w;
        s2 += v.x * v.x + v.y * v.y + v.z * v.z + v.w * v.w;
    }
#pragma unroll
    for (int o = 32; o > 0; o >>= 1) {
        s  += __shfl_down(s, o, 64);
        s2 += __shfl_down(s2, o, 64);
    }
    __shared__ float ls[4], ls2[4];
    int lane = threadIdx.x & 63, wvv = threadIdx.x >> 6;
    if (lane == 0) { ls[wvv] = s; ls2[wvv] = s2; }
    __syncthreads();
    if (threadIdx.x == 0) {
        float ts = 0.f, t2 = 0.f;
#pragma unroll
        for (int i = 0; i < 4; i++) { ts += ls[i]; t2 += ls2[i]; }
        atomicAdd(&stats[co], ts);
        atomicAdd(&stats[64 + co], t2);
    }
}

// ---------------- BN + ReLU: y = part0 + out + bias, normalize, write out ---
__global__ __launch_bounds__(256) void bn_kernel(float* __restrict__ y,
                                                 const float* __restrict__ part0,
                                                 const float* __restrict__ bias,
                                                 const float* __restrict__ stats,
                                                 const float* __restrict__ gamma,
                                                 const float* __restrict__ beta,
                                                 int split) {
    size_t base = (size_t)blockIdx.x * 1024;
    int co = (int)((base >> 14) & 63);
    const float inv_n = 1.f / 65536.f;
    float mean = stats[co] * inv_n;
    float var  = stats[64 + co] * inv_n - mean * mean;
    float sc = gamma[co] * rsqrtf(var + EPSV);
    float sh = beta[co] - mean * sc;
    sh += bias[co] * sc;                       // fold bias into shift
    float4* p = (float4*)(y + base);
    float4 v = p[threadIdx.x];
    if (split) {
        float4 u = ((const float4*)(part0 + base))[threadIdx.x];
        v.x += u.x; v.y += u.y; v.z += u.z; v.w += u.w;
    }
    v.x = fmaxf(fmaf(v.x, sc, sh), 0.f);
    v.y = fmaxf(fmaf(v.y, sc, sh), 0.f);
    v.z = fmaxf(fmaf(v.z, sc, sh), 0.f);
    v.w = fmaxf(fmaf(v.w, sc, sh), 0.f);
    p[threadIdx.x] = v;
}

extern "C" void kernel_launch(void* const* d_in, const int* in_sizes, int n_in,
                              void* d_out, int out_size, void* d_ws, size_t ws_size,
                              hipStream_t stream) {
    const float* x     = (const float*)d_in[0];
    const float* w_off = (const float*)d_in[1];
    const float* b_off = (const float*)d_in[2];
    const float* wmat  = (const float*)d_in[3];
    const float* bvec  = (const float*)d_in[4];
    const float* gamma = (const float*)d_in[5];
    const float* beta  = (const float*)d_in[6];
    float* out = (float*)d_out;

    char* ws = (char*)d_ws;
    float* stats          = (float*)ws;                   // 512 B
    unsigned short* w_bf  = (unsigned short*)(ws + 1024); // 73728 B
    unsigned short* woA   = (unsigned short*)(ws + 74752);// 36864 B
    float* off            = (float*)(ws + 139264);        // 7077888 B
    float* part0          = (float*)(ws + 7217152);       // 16777216 B
    const size_t need = 7217152 + 16777216;
    const int split = (ws_size >= need) ? 1 : 0;

    hipMemsetAsync(stats, 0, 512, stream);
    prep_kernel<<<144, 256, 0, stream>>>(wmat, w_off, w_bf, woA);
    off_conv_kernel<<<1024, 256, 0, stream>>>(x, woA, off);
    deform_kernel<<<split ? 2048 : 1024, 256, 0, stream>>>(x, w_bf, off, b_off,
                                                           out, part0, split);
    stats_kernel<<<1024, 256, 0, stream>>>(out, part0, bvec, stats, split);
    bn_kernel<<<4096, 256, 0, stream>>>(out, part0, bvec, stats, gamma, beta, split);
}